// Round 3
// baseline (95.841 us; speedup 1.0000x reference)
//
#include <hip/hip_runtime.h>
#include <math.h>

#define B_TOTAL 2048
#define I_TOTAL 2048
#define O_TOTAL 2048
#define KW 64
#define NIN 6
#define BLOCK 256

// ws layout:
//   sigw [O][64]  (lo[0:32], diff[32:64])      @ 0          512 KB
//   m32  [O][6]   int32                        @ 512 KB      48 KB
//   xT   [I][B]   x transposed                 @ 1 MB        16 MB
//   outT [O][B]   out transposed               @ 17 MB       16 MB
#define WS_SIGW 0
#define WS_M32  (512 * 1024)
#define WS_XT   (1024 * 1024)
#define WS_OUTT (WS_XT + B_TOTAL * I_TOTAL * 4)

// Prep: sigw[o][k<32] = sigmoid(table[o][k]); sigw[o][k>=32] = sig(k)-sig(k-32).
// mapping (int64 OR int32, auto-detected) -> int32 m32[o][i].
__global__ void prep_kernel(const float* __restrict__ table,
                            const unsigned int* __restrict__ map_raw,
                            float* __restrict__ sigw,
                            int* __restrict__ m32)
{
    int idx = blockIdx.x * blockDim.x + threadIdx.x;   // 0 .. O*KW-1
    int k = idx & 63;
    float s = 1.0f / (1.0f + __expf(-table[idx]));
    float v = s;
    if (k >= 32) {
        float s0 = 1.0f / (1.0f + __expf(-table[idx - 32]));
        v = s - s0;
    }
    sigw[idx] = v;

    if (idx < O_TOTAL * NIN) {
        // int64 little-endian, values < 2048 => odd u32 words all zero.
        bool is64 = ((map_raw[1] | map_raw[3] | map_raw[5] | map_raw[7]) == 0u);
        m32[idx] = is64 ? (int)map_raw[2 * idx] : (int)map_raw[idx];
    }
}

// 2048x2048 fp32 transpose, 64x64 tiles via LDS. Coalesced float4 both sides.
__global__ __launch_bounds__(256) void transpose_k(const float* __restrict__ src,
                                                   float* __restrict__ dst)
{
    __shared__ float tile[64][65];
    const int t  = threadIdx.x;
    const int r0 = blockIdx.y * 64;
    const int c0 = blockIdx.x * 64;
    const int rr = t >> 4;            // 0..15
    const int cc = (t & 15) << 2;     // 0,4,...,60
    #pragma unroll
    for (int p = 0; p < 4; ++p) {
        int r = p * 16 + rr;
        float4 v = *(const float4*)(src + (size_t)(r0 + r) * 2048 + c0 + cc);
        tile[r][cc + 0] = v.x; tile[r][cc + 1] = v.y;
        tile[r][cc + 2] = v.z; tile[r][cc + 3] = v.w;
    }
    __syncthreads();
    #pragma unroll
    for (int p = 0; p < 4; ++p) {
        int r = p * 16 + rr;          // row of dst tile = col of src tile
        float4 v;
        v.x = tile[cc + 0][r]; v.y = tile[cc + 1][r];
        v.z = tile[cc + 2][r]; v.w = tile[cc + 3][r];
        *(float4*)(dst + (size_t)(c0 + r) * 2048 + r0 + cc) = v;
    }
}

// Main: each wave owns ONE o (6 indices + 64 weights wave-uniform), lanes over b.
// xv loads are coalesced 256B reads of xT rows; zero gathers, zero LDS.
__global__ __launch_bounds__(BLOCK) void lut_main(
    const float* __restrict__ xT,
    const float* __restrict__ sigw,
    const int*   __restrict__ m32,
    float*       __restrict__ outT)
{
    const int wave = threadIdx.x >> 6;            // 0..3
    const int lane = threadIdx.x & 63;
    const int o    = blockIdx.y * 4 + wave;
    const int b0   = blockIdx.x * 512;

    float ww[KW];
    const float* wp = sigw + (size_t)o * KW;
    #pragma unroll
    for (int k = 0; k < KW; ++k) ww[k] = wp[k];   // same-address broadcast loads

    int m[NIN];
    #pragma unroll
    for (int i = 0; i < NIN; ++i) m[i] = m32[o * NIN + i];

    #pragma unroll
    for (int p = 0; p < 8; ++p) {
        const int b = b0 + p * 64 + lane;
        float xv[NIN];
        #pragma unroll
        for (int i = 0; i < NIN; ++i)
            xv[i] = xT[(size_t)m[i] * B_TOTAL + b];   // coalesced, L2/LLC-hot

        float t[32];
        #pragma unroll
        for (int j = 0; j < 32; ++j) t[j] = fmaf(xv[5], ww[j + 32], ww[j]);
        #pragma unroll
        for (int j = 0; j < 16; ++j) t[j] = fmaf(xv[4], t[j + 16] - t[j], t[j]);
        #pragma unroll
        for (int j = 0; j < 8;  ++j) t[j] = fmaf(xv[3], t[j + 8]  - t[j], t[j]);
        #pragma unroll
        for (int j = 0; j < 4;  ++j) t[j] = fmaf(xv[2], t[j + 4]  - t[j], t[j]);
        #pragma unroll
        for (int j = 0; j < 2;  ++j) t[j] = fmaf(xv[1], t[j + 2]  - t[j], t[j]);
        float res = fmaf(xv[0], t[1] - t[0], t[0]);

        outT[(size_t)o * B_TOTAL + b] = res;          // coalesced
    }
}

extern "C" void kernel_launch(void* const* d_in, const int* in_sizes, int n_in,
                              void* d_out, int out_size, void* d_ws, size_t ws_size,
                              hipStream_t stream)
{
    const float*        x       = (const float*)d_in[0];
    const float*        table   = (const float*)d_in[1];
    const unsigned int* map_raw = (const unsigned int*)d_in[2];
    float* out  = (float*)d_out;
    float* sigw = (float*)((char*)d_ws + WS_SIGW);
    int*   m32  = (int*)  ((char*)d_ws + WS_M32);
    float* xT   = (float*)((char*)d_ws + WS_XT);
    float* outT = (float*)((char*)d_ws + WS_OUTT);

    prep_kernel<<<(O_TOTAL * KW) / BLOCK, BLOCK, 0, stream>>>(table, map_raw, sigw, m32);
    transpose_k<<<dim3(32, 32), BLOCK, 0, stream>>>(x, xT);

    // waves = 2048 o * 4 b-chunks = 8192; block = 4 waves (4 o's, same b-chunk)
    lut_main<<<dim3(4, 512), BLOCK, 0, stream>>>(xT, sigw, m32, outT);

    transpose_k<<<dim3(32, 32), BLOCK, 0, stream>>>(outT, out);
}

// Round 4
// 95.291 us; speedup vs baseline: 1.0058x; 1.0058x over previous
//
#include <hip/hip_runtime.h>
#include <math.h>

#define B_TOTAL 2048
#define I_TOTAL 2048
#define O_TOTAL 2048
#define KW 64
#define NIN 6
#define BLOCK 256

// ws layout:
//   sigw [O][64]  (lo[0:32], diff[32:64])  @ 0        512 KB
//   m32  [O][6]   int32                    @ 512 KB    48 KB
//   xT   [I][B]   x transposed             @ 1 MB      16 MB
#define WS_SIGW 0
#define WS_M32  (512 * 1024)
#define WS_XT   (1024 * 1024)

// K1: 2048x2048 fp32 transpose (x -> xT) with prep fused in:
//   sigw[o][k<32] = sigmoid(table[o][k]); sigw[o][k>=32] = sig(k) - sig(k-32)
//   mapping (int64 OR int32, auto-detected) -> int32 m32[o][i]
__global__ __launch_bounds__(BLOCK) void xpose_prep(
    const float* __restrict__ x,
    const float* __restrict__ table,
    const unsigned int* __restrict__ map_raw,
    float* __restrict__ xT,
    float* __restrict__ sigw,
    int* __restrict__ m32)
{
    __shared__ float tile[64][65];
    const int t  = threadIdx.x;
    const int r0 = blockIdx.y * 64;
    const int c0 = blockIdx.x * 64;
    const int rr = t >> 4;            // 0..15
    const int cc = (t & 15) << 2;     // 0,4,...,60
    #pragma unroll
    for (int p = 0; p < 4; ++p) {
        int r = p * 16 + rr;
        float4 v = *(const float4*)(x + (size_t)(r0 + r) * I_TOTAL + c0 + cc);
        tile[r][cc + 0] = v.x; tile[r][cc + 1] = v.y;
        tile[r][cc + 2] = v.z; tile[r][cc + 3] = v.w;
    }

    // prep tail (first 512 blocks do sigmoid; first 48 do mapping)
    const int bid = blockIdx.y * gridDim.x + blockIdx.x;   // 0..1023
    const int gid = bid * BLOCK + t;
    if (gid < O_TOTAL * KW) {
        int k = gid & 63;
        float s = 1.0f / (1.0f + __expf(-table[gid]));
        float v = s;
        if (k >= 32) {
            float s0 = 1.0f / (1.0f + __expf(-table[gid - 32]));
            v = s - s0;
        }
        sigw[gid] = v;
    }
    if (gid < O_TOTAL * NIN) {
        // int64 little-endian, values < 2048 => odd u32 words all zero.
        bool is64 = ((map_raw[1] | map_raw[3] | map_raw[5] | map_raw[7]) == 0u);
        m32[gid] = is64 ? (int)map_raw[2 * gid] : (int)map_raw[gid];
    }

    __syncthreads();
    #pragma unroll
    for (int p = 0; p < 4; ++p) {
        int r = p * 16 + rr;          // row of dst tile = col of src tile
        float4 v;
        v.x = tile[cc + 0][r]; v.y = tile[cc + 1][r];
        v.z = tile[cc + 2][r]; v.w = tile[cc + 3][r];
        *(float4*)(xT + (size_t)(c0 + r) * B_TOTAL + r0 + cc) = v;
    }
}

// K2: block = 64o x 64b tile. 4 waves; each wave owns 16 o's sequentially,
// lanes over b. o is wave-uniform (readfirstlane) -> weights/indices load as
// scalar broadcasts; xT reads + out writes fully coalesced. Output tile is
// transposed through LDS so `out` is written in its native [b][o] layout.
// grid(32 ot, 32 bt): o-tile is the FAST block dim -> the 32 blocks sharing
// an o-tile's xT rows land on the same XCD (linear id % 8 == ot % 8).
__global__ __launch_bounds__(BLOCK) void lut_main(
    const float* __restrict__ xT,
    const float* __restrict__ sigw,
    const int*   __restrict__ m32,
    float*       __restrict__ out)
{
    __shared__ float tile[64][65];
    const int tid  = threadIdx.x;
    const int lane = tid & 63;
    const int wv   = __builtin_amdgcn_readfirstlane(tid >> 6);   // 0..3, uniform
    const int o0   = blockIdx.x * 64;
    const int b    = blockIdx.y * 64 + lane;

    #pragma unroll 2
    for (int j = 0; j < 16; ++j) {
        const int o = o0 + wv * 16 + j;                 // wave-uniform
        const float* __restrict__ wp = sigw + (size_t)o * KW;
        const int*   __restrict__ mp = m32 + o * NIN;

        int m[NIN];
        #pragma unroll
        for (int i = 0; i < NIN; ++i) m[i] = mp[i];     // scalar loads

        float xv[NIN];
        #pragma unroll
        for (int i = 0; i < NIN; ++i)
            xv[i] = xT[(size_t)m[i] * B_TOTAL + b];     // coalesced 256B rows

        float ww[KW];
        #pragma unroll
        for (int k = 0; k < KW; ++k) ww[k] = wp[k];     // s_load broadcast

        float t[32];
        #pragma unroll
        for (int q = 0; q < 32; ++q) t[q] = fmaf(xv[5], ww[q + 32], ww[q]);
        #pragma unroll
        for (int q = 0; q < 16; ++q) t[q] = fmaf(xv[4], t[q + 16] - t[q], t[q]);
        #pragma unroll
        for (int q = 0; q < 8;  ++q) t[q] = fmaf(xv[3], t[q + 8]  - t[q], t[q]);
        #pragma unroll
        for (int q = 0; q < 4;  ++q) t[q] = fmaf(xv[2], t[q + 4]  - t[q], t[q]);
        #pragma unroll
        for (int q = 0; q < 2;  ++q) t[q] = fmaf(xv[1], t[q + 2]  - t[q], t[q]);
        float res = fmaf(xv[0], t[1] - t[0], t[0]);

        tile[wv * 16 + j][lane] = res;                  // (o_local+lane)%32: 2-way, free
    }

    __syncthreads();
    #pragma unroll
    for (int r = 0; r < 16; ++r) {
        const int e  = r * BLOCK + tid;
        const int bl = e >> 6;                          // wave-uniform
        const int ol = e & 63;                          // lanes over o
        out[(size_t)(blockIdx.y * 64 + bl) * O_TOTAL + o0 + ol] = tile[ol][bl];
    }
}

extern "C" void kernel_launch(void* const* d_in, const int* in_sizes, int n_in,
                              void* d_out, int out_size, void* d_ws, size_t ws_size,
                              hipStream_t stream)
{
    const float*        x       = (const float*)d_in[0];
    const float*        table   = (const float*)d_in[1];
    const unsigned int* map_raw = (const unsigned int*)d_in[2];
    float* out  = (float*)d_out;
    float* sigw = (float*)((char*)d_ws + WS_SIGW);
    int*   m32  = (int*)  ((char*)d_ws + WS_M32);
    float* xT   = (float*)((char*)d_ws + WS_XT);

    xpose_prep<<<dim3(32, 32), BLOCK, 0, stream>>>(x, table, map_raw, xT, sigw, m32);
    lut_main<<<dim3(32, 32), BLOCK, 0, stream>>>(xT, sigw, m32, out);
}

// Round 5
// 86.038 us; speedup vs baseline: 1.1139x; 1.1075x over previous
//
#include <hip/hip_runtime.h>
#include <math.h>

#define B_TOTAL 2048
#define I_TOTAL 2048
#define O_TOTAL 2048
#define KW 64
#define NIN 6
#define BLOCK 256
#define TILE_B 16          // b-rows per block
#define CH 4               // rows staged in LDS at a time (32 KB)
#define BBLOCKS (B_TOTAL / TILE_B)  /* 128 */
#define OBLOCKS (O_TOTAL / BLOCK)   /* 8   */

typedef __attribute__((ext_vector_type(2))) float f2;

// ws layout:
//   wP   [32][O] f2 {base=sig(w[2j]), diff=sig(w[2j+1])-sig(w[2j])}   512 KB
//   m32T [6][O]  int32                                                 48 KB
#define WS_WP  0
#define WS_M32 (32 * O_TOTAL * sizeof(f2))

// Prep: pair-wise sigmoid weights (leaf level = bit0, adjacent k) in [j][o]
// layout (coalesced dwordx2 loads in main); mapping int64/int32 auto-detected
// -> transposed int32 m32T[i][o].
__global__ void prep_kernel(const float* __restrict__ table,
                            const unsigned int* __restrict__ map_raw,
                            f2* __restrict__ wP,
                            int* __restrict__ m32T)
{
    int idx = blockIdx.x * blockDim.x + threadIdx.x;   // 0 .. O*32-1
    int o = idx >> 5, j = idx & 31;
    float s0 = 1.0f / (1.0f + __expf(-table[o * KW + 2 * j]));
    float s1 = 1.0f / (1.0f + __expf(-table[o * KW + 2 * j + 1]));
    f2 v; v.x = s0; v.y = s1 - s0;
    wP[j * O_TOTAL + o] = v;

    if (idx < O_TOTAL * NIN) {
        // int64 little-endian, values < 2048 => odd u32 words all zero.
        bool is64 = ((map_raw[1] | map_raw[3] | map_raw[5] | map_raw[7]) == 0u);
        int val = is64 ? (int)map_raw[2 * idx] : (int)map_raw[idx];
        int oo = idx / NIN, ii = idx - oo * NIN;
        m32T[ii * O_TOTAL + oo] = val;
    }
}

// Main: lanes over o (coalesced weights/mapping/out), x rows staged in LDS,
// per-(b,o) 6 random-bank ds_read gathers + depth-first 6-level multilinear
// tree (live set ~12 regs vs 32 breadth-first -> 4 waves/SIMD).
__global__ __launch_bounds__(BLOCK, 4) void lut_main(
    const float* __restrict__ x,
    const f2*    __restrict__ wP,
    const int*   __restrict__ m32T,
    float*       __restrict__ out)
{
    __shared__ float xs[CH * I_TOTAL];   // 32 KB

    const int o  = blockIdx.y * BLOCK + threadIdx.x;
    const int b0 = blockIdx.x * TILE_B;

    // 32 weight pairs -> registers (64 VGPRs, persistent), coalesced 8B loads
    f2 ww[32];
    #pragma unroll
    for (int j = 0; j < 32; ++j) ww[j] = wP[j * O_TOTAL + o];

    int m[NIN];
    #pragma unroll
    for (int i = 0; i < NIN; ++i) m[i] = m32T[i * O_TOTAL + o];

    for (int c = 0; c < TILE_B / CH; ++c) {
        __syncthreads();
        // stage CH rows cooperatively: 2048 float4 by 256 threads = 8 each
        const float4* src = (const float4*)(x + (size_t)(b0 + c * CH) * I_TOTAL);
        float4* dst = (float4*)xs;
        #pragma unroll
        for (int t = 0; t < (CH * I_TOTAL / 4) / BLOCK; ++t)
            dst[t * BLOCK + threadIdx.x] = src[t * BLOCK + threadIdx.x];
        __syncthreads();

        #pragma unroll
        for (int cr = 0; cr < CH; ++cr) {
            const float* xr = xs + cr * I_TOTAL;
            float xv[NIN];
            #pragma unroll
            for (int i = 0; i < NIN; ++i) xv[i] = xr[m[i]];   // LDS gather

            // depth-first multilinear tree: bit0 at leaves (precomp diffs)
            float a5[2];
            #pragma unroll
            for (int h5 = 0; h5 < 2; ++h5) {
                float a4[2];
                #pragma unroll
                for (int h4 = 0; h4 < 2; ++h4) {
                    float a3[2];
                    #pragma unroll
                    for (int h3 = 0; h3 < 2; ++h3) {
                        float a2[2];
                        #pragma unroll
                        for (int h2 = 0; h2 < 2; ++h2) {
                            float a1[2];
                            #pragma unroll
                            for (int h1 = 0; h1 < 2; ++h1) {
                                int j = (((h5 * 2 + h4) * 2 + h3) * 2 + h2) * 2 + h1;
                                f2 w = ww[j];
                                a1[h1] = fmaf(xv[0], w.y, w.x);
                            }
                            a2[h2] = fmaf(xv[1], a1[1] - a1[0], a1[0]);
                        }
                        a3[h3] = fmaf(xv[2], a2[1] - a2[0], a2[0]);
                    }
                    a4[h4] = fmaf(xv[3], a3[1] - a3[0], a3[0]);
                }
                a5[h5] = fmaf(xv[4], a4[1] - a4[0], a4[0]);
            }
            float res = fmaf(xv[5], a5[1] - a5[0], a5[0]);

            out[(size_t)(b0 + c * CH + cr) * O_TOTAL + o] = res;  // coalesced
        }
    }
}

extern "C" void kernel_launch(void* const* d_in, const int* in_sizes, int n_in,
                              void* d_out, int out_size, void* d_ws, size_t ws_size,
                              hipStream_t stream)
{
    const float*        x       = (const float*)d_in[0];
    const float*        table   = (const float*)d_in[1];
    const unsigned int* map_raw = (const unsigned int*)d_in[2];
    float* out  = (float*)d_out;
    f2*    wP   = (f2*) ((char*)d_ws + WS_WP);
    int*   m32T = (int*)((char*)d_ws + WS_M32);

    prep_kernel<<<(O_TOTAL * KW / 2) / BLOCK, BLOCK, 0, stream>>>(table, map_raw, wP, m32T);

    // grid x = b-tile (fast dim): the 8 o-blocks sharing a b-tile's x rows
    // land on the same XCD (128 % 8 == 0) -> x rows hit in that XCD's L2.
    dim3 grid(BBLOCKS, OBLOCKS);
    lut_main<<<grid, dim3(BLOCK), 0, stream>>>(x, wP, m32T, out);
}